// Round 1
// baseline (817.485 us; speedup 1.0000x reference)
//
#include <hip/hip_runtime.h>

// NeuralIF GraphNet: 3 layers x (lower GraphNet, upper GraphNet).
// Edge MLP: in 26 = [g(8), x[row](8), x[col](8), e_prev(1), skip(1)] -> 32 relu -> 1
// Node MLP: in 17 = [g(8), x(8), seg_mean(1)] -> 32 relu -> 8
// Global MLP: in 17 = [n_mean(8), e_mean(1), g(8)] -> 32 relu -> 8 (fused into node
// kernel's last block via done-counter).
// Final layer: lower edge kernel writes l_vals to d_out[0:E), last upper edge
// kernel (no agg needed) writes u_vals to d_out[E:2E), exp() on diagonal.

__device__ __forceinline__ float wave_sum(float v) {
#pragma unroll
    for (int off = 32; off > 0; off >>= 1) v += __shfl_down(v, off, 64);
    return v;
}

template <bool COUNT, bool SKIP, bool AGG, bool VALS, bool STORE>
__global__ __launch_bounds__(256) void edge_kernel(
    const float4* __restrict__ xf,       // node features (N,8) as float4 pairs
    const int* __restrict__ rows, const int* __restrict__ cols,
    const float* __restrict__ eprev,     // previous edge embedding (E)
    const float* __restrict__ skipattr,  // original attr (skip col), if SKIP
    const float* __restrict__ W1,        // 26x32 slice (row-major k,j)
    const float* __restrict__ b1,        // 32
    const float* __restrict__ W2,        // 32
    const float* __restrict__ b2,        // 1
    const float* __restrict__ gbuf,      // 8 (current global)
    float* __restrict__ e_out,           // edge emb store (STORE)
    float* __restrict__ vals_out,        // final output segment (VALS)
    float* __restrict__ agg_sum,         // N (AGG)
    int* __restrict__ cnt,               // N (COUNT)
    float* __restrict__ ebins,           // 64 partial sums for e-mean (AGG)
    int E) {
    __shared__ float biasE[32];
    __shared__ float wpart[4];
    const int t = threadIdx.x;
    if (t < 32) {
        // fold uniform global contribution + b1 into per-pass bias (once/block)
        float v = b1[t];
#pragma unroll
        for (int k = 0; k < 8; ++k) v = fmaf(gbuf[k], W1[k * 32 + t], v);
        biasE[t] = v;
    }
    __syncthreads();
    const int e = blockIdx.x * 256 + t;
    const bool valid = e < E;
    const int idx = valid ? e : 0;
    const int r = rows[idx];
    const int c = cols[idx];
    const float4 xr0 = xf[2 * r], xr1 = xf[2 * r + 1];
    const float4 xc0 = xf[2 * c], xc1 = xf[2 * c + 1];
    float in[18] = {xr0.x, xr0.y, xr0.z, xr0.w, xr1.x, xr1.y, xr1.z, xr1.w,
                    xc0.x, xc0.y, xc0.z, xc0.w, xc1.x, xc1.y, xc1.z, xc1.w,
                    eprev[idx], 0.0f};
    if constexpr (SKIP) in[17] = skipattr[idx];
    float h[32];
#pragma unroll
    for (int j = 0; j < 8; ++j) {
        const float4 b = reinterpret_cast<const float4*>(biasE)[j];
        h[4 * j + 0] = b.x; h[4 * j + 1] = b.y;
        h[4 * j + 2] = b.z; h[4 * j + 3] = b.w;
    }
    const float* __restrict__ Wk = W1 + 8 * 32;  // rows 8..25 (x[row],x[col],attr)
#pragma unroll
    for (int k = 0; k < 18; ++k) {
        const float v = in[k];
#pragma unroll
        for (int j = 0; j < 32; ++j) h[j] = fmaf(v, Wk[k * 32 + j], h[j]);
    }
    float out = b2[0];
#pragma unroll
    for (int j = 0; j < 32; ++j) out = fmaf(fmaxf(h[j], 0.0f), W2[j], out);

    if (valid) {
        if constexpr (STORE) e_out[e] = out;
        if constexpr (VALS) vals_out[e] = (r == c) ? expf(out) : out;
        if constexpr (AGG) atomicAdd(&agg_sum[r], out);
        if constexpr (COUNT) atomicAdd(&cnt[r], 1);
    }
    if constexpr (AGG) {
        const float s = wave_sum(valid ? out : 0.0f);
        if ((t & 63) == 0) wpart[t >> 6] = s;
        __syncthreads();
        if (t == 0)
            atomicAdd(&ebins[blockIdx.x & 63],
                      wpart[0] + wpart[1] + wpart[2] + wpart[3]);
    }
}

template <bool STORE_N>
__global__ __launch_bounds__(256) void node_kernel(
    const float4* __restrict__ xf,  // node features (N,8): x or l_n
    const float* __restrict__ agg_sum, const int* __restrict__ cnt,
    const float* __restrict__ gbuf,
    const float* __restrict__ nW1, const float* __restrict__ nb1,
    const float* __restrict__ nW2, const float* __restrict__ nb2,
    float* __restrict__ n_out,   // l_n (8N) if STORE_N
    const float* __restrict__ ebins,  // 64
    float* __restrict__ n_sum,   // 8
    int* __restrict__ done,
    const float* __restrict__ gW1, const float* __restrict__ gb1,
    const float* __restrict__ gW2, const float* __restrict__ gb2,
    float* __restrict__ g_out,   // 8 (same buffer as gbuf)
    int N, float inv_E) {
    __shared__ float biasN[32];
    __shared__ float npart[4][8];
    const int t = threadIdx.x;
    if (t < 32) {
        float v = nb1[t];
#pragma unroll
        for (int k = 0; k < 8; ++k) v = fmaf(gbuf[k], nW1[k * 32 + t], v);
        biasN[t] = v;
    }
    __syncthreads();
    const int n = blockIdx.x * 256 + t;
    const bool valid = n < N;
    const int idx = valid ? n : 0;
    const float4 x0 = xf[2 * idx], x1 = xf[2 * idx + 1];
    const float agg = agg_sum[idx] / fmaxf((float)cnt[idx], 1.0f);
    float in[9] = {x0.x, x0.y, x0.z, x0.w, x1.x, x1.y, x1.z, x1.w, agg};
    float h[32];
#pragma unroll
    for (int j = 0; j < 8; ++j) {
        const float4 b = reinterpret_cast<const float4*>(biasN)[j];
        h[4 * j + 0] = b.x; h[4 * j + 1] = b.y;
        h[4 * j + 2] = b.z; h[4 * j + 3] = b.w;
    }
    const float* __restrict__ Wk = nW1 + 8 * 32;
#pragma unroll
    for (int k = 0; k < 9; ++k) {
        const float v = in[k];
#pragma unroll
        for (int j = 0; j < 32; ++j) h[j] = fmaf(v, Wk[k * 32 + j], h[j]);
    }
    float o[8];
#pragma unroll
    for (int q = 0; q < 8; ++q) o[q] = nb2[q];
#pragma unroll
    for (int j = 0; j < 32; ++j) {
        const float hv = fmaxf(h[j], 0.0f);
#pragma unroll
        for (int q = 0; q < 8; ++q) o[q] = fmaf(hv, nW2[j * 8 + q], o[q]);
    }
    if constexpr (STORE_N) {
        if (valid) {
            reinterpret_cast<float4*>(n_out)[2 * n] =
                make_float4(o[0], o[1], o[2], o[3]);
            reinterpret_cast<float4*>(n_out)[2 * n + 1] =
                make_float4(o[4], o[5], o[6], o[7]);
        }
    }
#pragma unroll
    for (int q = 0; q < 8; ++q) {
        const float s = wave_sum(valid ? o[q] : 0.0f);
        if ((t & 63) == 0) npart[t >> 6][q] = s;
    }
    __syncthreads();
    if (t < 8)
        atomicAdd(&n_sum[t], npart[0][t] + npart[1][t] + npart[2][t] + npart[3][t]);
    __threadfence();
    __syncthreads();
    if (t == 0) {
        const int old = atomicAdd(done, 1);
        if (old == (int)gridDim.x - 1) {
            // last block: fused global-MLP update
            __threadfence();
            float gin[17];
#pragma unroll
            for (int k = 0; k < 8; ++k)
                gin[k] = atomicAdd(&n_sum[k], 0.0f) / (float)N;
            float es = 0.0f;
            for (int b = 0; b < 64; ++b) es += ebins[b];
            gin[8] = es * inv_E;
#pragma unroll
            for (int k = 0; k < 8; ++k) gin[9 + k] = gbuf[k];
            float go[8];
#pragma unroll
            for (int q = 0; q < 8; ++q) go[q] = gb2[q];
            for (int j = 0; j < 32; ++j) {
                float hv = gb1[j];
                for (int k = 0; k < 17; ++k) hv = fmaf(gin[k], gW1[k * 32 + j], hv);
                hv = fmaxf(hv, 0.0f);
                for (int q = 0; q < 8; ++q) go[q] = fmaf(hv, gW2[j * 8 + q], go[q]);
            }
#pragma unroll
            for (int q = 0; q < 8; ++q) g_out[q] = go[q];
        }
    }
}

extern "C" void kernel_launch(void* const* d_in, const int* in_sizes, int n_in,
                              void* d_out, int out_size, void* d_ws,
                              size_t ws_size, hipStream_t stream) {
    const float* x = (const float*)d_in[0];
    const int* l_ei = (const int*)d_in[1];
    const int* u_ei = (const int*)d_in[2];
    const float* l_attr = (const float*)d_in[3];
    const float* u_attr = (const float*)d_in[4];
    const float* eW1 = (const float*)d_in[5];
    const float* eb1 = (const float*)d_in[6];
    const float* eW2 = (const float*)d_in[7];
    const float* eb2 = (const float*)d_in[8];
    const float* nW1 = (const float*)d_in[9];
    const float* nb1 = (const float*)d_in[10];
    const float* nW2 = (const float*)d_in[11];
    const float* nb2 = (const float*)d_in[12];
    const float* gW1 = (const float*)d_in[13];
    const float* gb1 = (const float*)d_in[14];
    const float* gW2 = (const float*)d_in[15];
    const float* gb2 = (const float*)d_in[16];

    const int E = in_sizes[3];      // 1,100,000
    const int N = in_sizes[0] / 8;  // 100,000

    // workspace layout (floats)
    float* ws = (float*)d_ws;
    float* l_e = ws;                     // E
    float* u_e = l_e + E;                // E
    float* l_n = u_e + E;                // 8N (float4-aligned: 2E*4 bytes % 16 == 0)
    float* dyn = l_n + (size_t)8 * N;    // [agg N][ebins 64][n_sum 8][done 1]
    float* agg = dyn;
    float* ebins = dyn + N;
    float* n_sum = ebins + 64;
    int* done = (int*)(n_sum + 8);
    int* cnt_l = (int*)(dyn + N + 73);   // N ints
    int* cnt_u = cnt_l + N;              // N ints
    float* gbuf = (float*)(cnt_u + N);   // 8 floats

    const int* lr = l_ei;
    const int* lc = l_ei + E;
    const int* ur = u_ei;
    const int* uc = u_ei + E;
    const int eg = (E + 255) / 256;
    const int ng = (N + 255) / 256;
    const float invE = 1.0f / (float)E;
    float* outL = (float*)d_out;
    float* outU = outL + E;

    // zero counts + global (persist across the whole call)
    hipMemsetAsync(cnt_l, 0, (size_t)(2 * N) * sizeof(int) + 8 * sizeof(float),
                   stream);

    for (int i = 0; i < 3; ++i) {
        const size_t lo = (size_t)i;      // lower-block slice
        const size_t up = (size_t)(3 + i);  // upper-block slice

        // ---------------- lower GraphNet ----------------
        hipMemsetAsync(dyn, 0, (size_t)(N + 73) * sizeof(float), stream);
        const float* eprev = (i == 0) ? l_attr : l_e;
        if (i == 0)
            edge_kernel<true, false, true, false, true><<<eg, 256, 0, stream>>>(
                (const float4*)x, lr, lc, eprev, l_attr, eW1 + lo * 832,
                eb1 + lo * 32, eW2 + lo * 32, eb2 + lo, gbuf, l_e, outL, agg,
                cnt_l, ebins, E);
        else if (i == 1)
            edge_kernel<false, true, true, false, true><<<eg, 256, 0, stream>>>(
                (const float4*)x, lr, lc, eprev, l_attr, eW1 + lo * 832,
                eb1 + lo * 32, eW2 + lo * 32, eb2 + lo, gbuf, l_e, outL, agg,
                cnt_l, ebins, E);
        else
            edge_kernel<false, true, true, true, false><<<eg, 256, 0, stream>>>(
                (const float4*)x, lr, lc, eprev, l_attr, eW1 + lo * 832,
                eb1 + lo * 32, eW2 + lo * 32, eb2 + lo, gbuf, l_e, outL, agg,
                cnt_l, ebins, E);
        node_kernel<true><<<ng, 256, 0, stream>>>(
            (const float4*)x, agg, cnt_l, gbuf, nW1 + lo * 544, nb1 + lo * 32,
            nW2 + lo * 256, nb2 + lo * 8, l_n, ebins, n_sum, done,
            gW1 + lo * 544, gb1 + lo * 32, gW2 + lo * 256, gb2 + lo * 8, gbuf,
            N, invE);

        // ---------------- upper GraphNet ----------------
        if (i < 2) {
            hipMemsetAsync(dyn, 0, (size_t)(N + 73) * sizeof(float), stream);
            const float* ueprev = (i == 0) ? u_attr : u_e;
            if (i == 0)
                edge_kernel<true, false, true, false, true>
                    <<<eg, 256, 0, stream>>>((const float4*)l_n, ur, uc, ueprev,
                                             nullptr, eW1 + up * 832,
                                             eb1 + up * 32, eW2 + up * 32,
                                             eb2 + up, gbuf, u_e, nullptr, agg,
                                             cnt_u, ebins, E);
            else
                edge_kernel<false, false, true, false, true>
                    <<<eg, 256, 0, stream>>>((const float4*)l_n, ur, uc, ueprev,
                                             nullptr, eW1 + up * 832,
                                             eb1 + up * 32, eW2 + up * 32,
                                             eb2 + up, gbuf, u_e, nullptr, agg,
                                             cnt_u, ebins, E);
            node_kernel<false><<<ng, 256, 0, stream>>>(
                (const float4*)l_n, agg, cnt_u, gbuf, nW1 + up * 544,
                nb1 + up * 32, nW2 + up * 256, nb2 + up * 8, nullptr, ebins,
                n_sum, done, gW1 + up * 544, gb1 + up * 32, gW2 + up * 256,
                gb2 + up * 8, gbuf, N, invE);
        } else {
            // final upper GraphNet: only edge output is needed -> write u_vals
            edge_kernel<false, false, false, true, false>
                <<<eg, 256, 0, stream>>>((const float4*)l_n, ur, uc, u_e,
                                         nullptr, eW1 + up * 832, eb1 + up * 32,
                                         eW2 + up * 32, eb2 + up, gbuf, nullptr,
                                         outU, nullptr, nullptr, nullptr, E);
        }
    }
}

// Round 2
// 729.660 us; speedup vs baseline: 1.1204x; 1.1204x over previous
//
#include <hip/hip_runtime.h>

// NeuralIF GraphNet: 3 layers x (lower GraphNet, upper GraphNet).
// R1 change: all scattered global atomics removed. Per-call bucketed edge
// lists (bucket = row>>9, 512 rows/bucket) built via hist->scan->scatter with
// coalesced writes; aggregation = one block per bucket, LDS bins, plain
// coalesced stores of agg/cnt. Edge MLP kernels do only streaming/gather
// reads + streaming writes + a 64-bin e-mean block reduction.

typedef unsigned int u32;

#define NB_SHIFT 9
#define NB_SIZE 512

__device__ __forceinline__ float wave_sum(float v) {
#pragma unroll
    for (int off = 32; off > 0; off >>= 1) v += __shfl_down(v, off, 64);
    return v;
}

// ---------------- bucketed-list build (once per call) ----------------

__global__ __launch_bounds__(256) void hist_kernel(
    const int* __restrict__ lr, const int* __restrict__ ur,
    u32* __restrict__ hist, int E, int B) {
    __shared__ u32 h[256];
    const int t = threadIdx.x;
    if (t < B) h[t] = 0;
    __syncthreads();
    const int s = blockIdx.y;
    const int* rows = s ? ur : lr;
    for (int i = blockIdx.x * 256 + t; i < E; i += gridDim.x * 256)
        atomicAdd(&h[rows[i] >> NB_SHIFT], 1u);
    __syncthreads();
    if (t < B && h[t]) atomicAdd(&hist[s * B + t], h[t]);
}

__global__ void scan_kernel(const u32* __restrict__ hist, u32* __restrict__ offs,
                            u32* __restrict__ cur, int B) {
    if (threadIdx.x == 0) {
        for (int s = 0; s < 2; ++s) {
            u32 acc = 0;
            for (int b = 0; b < B; ++b) {
                offs[s * (B + 1) + b] = acc;
                cur[s * B + b] = acc;
                acc += hist[s * B + b];
            }
            offs[s * (B + 1) + B] = acc;
        }
    }
}

#define SCHUNK 4096
__global__ __launch_bounds__(256) void scatter_kernel(
    const int* __restrict__ lr, const int* __restrict__ ur,
    u32* __restrict__ cur, u32* __restrict__ list, int E, int B) {
    __shared__ u32 lcnt[256], lbase[256];
    const int t = threadIdx.x;
    const int s = blockIdx.y;
    const int* rows = s ? ur : lr;
    u32* mylist = list + (size_t)s * E;
    if (t < B) lcnt[t] = 0;
    __syncthreads();
    const int base_e = blockIdx.x * SCHUNK;
#pragma unroll
    for (int k = 0; k < SCHUNK / 256; ++k) {
        const int e = base_e + k * 256 + t;
        if (e < E) atomicAdd(&lcnt[rows[e] >> NB_SHIFT], 1u);
    }
    __syncthreads();
    if (t < B) {
        const u32 c = lcnt[t];
        lbase[t] = c ? atomicAdd(&cur[s * B + t], c) : 0u;
        lcnt[t] = 0;
    }
    __syncthreads();
#pragma unroll
    for (int k = 0; k < SCHUNK / 256; ++k) {
        const int e = base_e + k * 256 + t;
        if (e < E) {
            const int b = rows[e] >> NB_SHIFT;
            const u32 pos = lbase[b] + atomicAdd(&lcnt[b], 1u);
            mylist[pos] = (u32)e;
        }
    }
}

// ---------------- aggregation: one block owns one bucket ----------------

template <bool COUNT>
__global__ __launch_bounds__(1024) void agg_kernel(
    const u32* __restrict__ list, const u32* __restrict__ offs,
    const int* __restrict__ rows, const float* __restrict__ e_emb,
    float* __restrict__ agg, float* __restrict__ cntf, int N) {
    __shared__ float sbin[NB_SIZE];
    __shared__ float cbin[NB_SIZE];
    const int t = threadIdx.x;
    const int b = blockIdx.x;
    if (t < NB_SIZE) {
        sbin[t] = 0.0f;
        if constexpr (COUNT) cbin[t] = 0.0f;
    }
    __syncthreads();
    const u32 beg = offs[b], end = offs[b + 1];
    for (u32 i = beg + t; i < end; i += 1024) {
        const u32 eid = list[i];
        const float v = e_emb[eid];
        const int r = rows[eid];
        atomicAdd(&sbin[r & (NB_SIZE - 1)], v);
        if constexpr (COUNT) atomicAdd(&cbin[r & (NB_SIZE - 1)], 1.0f);
    }
    __syncthreads();
    const int n0 = b << NB_SHIFT;
    if (t < NB_SIZE && n0 + t < N) {
        agg[n0 + t] = sbin[t];
        if constexpr (COUNT) cntf[n0 + t] = cbin[t];
    }
}

// ---------------- edge MLP ----------------

template <bool SKIP, bool GAGG, bool VALS, bool STORE>
__global__ __launch_bounds__(256) void edge_kernel(
    const float4* __restrict__ xf,       // node features (N,8) as float4 pairs
    const int* __restrict__ rows, const int* __restrict__ cols,
    const float* __restrict__ eprev,     // previous edge embedding (E)
    const float* __restrict__ skipattr,  // original attr (skip col), if SKIP
    const float* __restrict__ W1,        // 26x32 slice (row-major k,j)
    const float* __restrict__ b1,        // 32
    const float* __restrict__ W2,        // 32
    const float* __restrict__ b2,        // 1
    const float* __restrict__ gbuf,      // 8 (current global)
    float* __restrict__ e_out,           // edge emb store (STORE)
    float* __restrict__ vals_out,        // final output segment (VALS)
    float* __restrict__ ebins,           // 64 partial sums for e-mean (GAGG)
    int E) {
    __shared__ float biasE[32];
    __shared__ float wpart[4];
    const int t = threadIdx.x;
    if (t < 32) {
        // fold uniform global contribution + b1 into per-pass bias (once/block)
        float v = b1[t];
#pragma unroll
        for (int k = 0; k < 8; ++k) v = fmaf(gbuf[k], W1[k * 32 + t], v);
        biasE[t] = v;
    }
    __syncthreads();
    const int e = blockIdx.x * 256 + t;
    const bool valid = e < E;
    const int idx = valid ? e : 0;
    const int r = rows[idx];
    const int c = cols[idx];
    const float4 xr0 = xf[2 * r], xr1 = xf[2 * r + 1];
    const float4 xc0 = xf[2 * c], xc1 = xf[2 * c + 1];
    float in[18] = {xr0.x, xr0.y, xr0.z, xr0.w, xr1.x, xr1.y, xr1.z, xr1.w,
                    xc0.x, xc0.y, xc0.z, xc0.w, xc1.x, xc1.y, xc1.z, xc1.w,
                    eprev[idx], 0.0f};
    if constexpr (SKIP) in[17] = skipattr[idx];
    float h[32];
#pragma unroll
    for (int j = 0; j < 8; ++j) {
        const float4 b = reinterpret_cast<const float4*>(biasE)[j];
        h[4 * j + 0] = b.x; h[4 * j + 1] = b.y;
        h[4 * j + 2] = b.z; h[4 * j + 3] = b.w;
    }
    const float* __restrict__ Wk = W1 + 8 * 32;  // rows 8..25 (x[row],x[col],attr)
#pragma unroll
    for (int k = 0; k < 18; ++k) {
        const float v = in[k];
#pragma unroll
        for (int j = 0; j < 32; ++j) h[j] = fmaf(v, Wk[k * 32 + j], h[j]);
    }
    float out = b2[0];
#pragma unroll
    for (int j = 0; j < 32; ++j) out = fmaf(fmaxf(h[j], 0.0f), W2[j], out);

    if (valid) {
        if constexpr (STORE) e_out[e] = out;
        if constexpr (VALS) vals_out[e] = (r == c) ? expf(out) : out;
    }
    if constexpr (GAGG) {
        const float s = wave_sum(valid ? out : 0.0f);
        if ((t & 63) == 0) wpart[t >> 6] = s;
        __syncthreads();
        if (t == 0)
            atomicAdd(&ebins[blockIdx.x & 63],
                      wpart[0] + wpart[1] + wpart[2] + wpart[3]);
    }
}

// ---------------- node MLP (+ fused global MLP in last block) ----------------

template <bool STORE_N>
__global__ __launch_bounds__(256) void node_kernel(
    const float4* __restrict__ xf,  // node features (N,8): x or l_n
    const float* __restrict__ agg_sum, const float* __restrict__ cntf,
    const float* __restrict__ gbuf,
    const float* __restrict__ nW1, const float* __restrict__ nb1,
    const float* __restrict__ nW2, const float* __restrict__ nb2,
    float* __restrict__ n_out,        // l_n (8N) if STORE_N
    const float* __restrict__ ebins,  // 64
    float* __restrict__ n_sum,        // 8
    int* __restrict__ done,
    const float* __restrict__ gW1, const float* __restrict__ gb1,
    const float* __restrict__ gW2, const float* __restrict__ gb2,
    float* __restrict__ g_out,  // 8 (same buffer as gbuf)
    int N, float inv_E) {
    __shared__ float biasN[32];
    __shared__ float npart[4][8];
    const int t = threadIdx.x;
    if (t < 32) {
        float v = nb1[t];
#pragma unroll
        for (int k = 0; k < 8; ++k) v = fmaf(gbuf[k], nW1[k * 32 + t], v);
        biasN[t] = v;
    }
    __syncthreads();
    const int n = blockIdx.x * 256 + t;
    const bool valid = n < N;
    const int idx = valid ? n : 0;
    const float4 x0 = xf[2 * idx], x1 = xf[2 * idx + 1];
    const float agg = agg_sum[idx] / fmaxf(cntf[idx], 1.0f);
    float in[9] = {x0.x, x0.y, x0.z, x0.w, x1.x, x1.y, x1.z, x1.w, agg};
    float h[32];
#pragma unroll
    for (int j = 0; j < 8; ++j) {
        const float4 b = reinterpret_cast<const float4*>(biasN)[j];
        h[4 * j + 0] = b.x; h[4 * j + 1] = b.y;
        h[4 * j + 2] = b.z; h[4 * j + 3] = b.w;
    }
    const float* __restrict__ Wk = nW1 + 8 * 32;
#pragma unroll
    for (int k = 0; k < 9; ++k) {
        const float v = in[k];
#pragma unroll
        for (int j = 0; j < 32; ++j) h[j] = fmaf(v, Wk[k * 32 + j], h[j]);
    }
    float o[8];
#pragma unroll
    for (int q = 0; q < 8; ++q) o[q] = nb2[q];
#pragma unroll
    for (int j = 0; j < 32; ++j) {
        const float hv = fmaxf(h[j], 0.0f);
#pragma unroll
        for (int q = 0; q < 8; ++q) o[q] = fmaf(hv, nW2[j * 8 + q], o[q]);
    }
    if constexpr (STORE_N) {
        if (valid) {
            reinterpret_cast<float4*>(n_out)[2 * n] =
                make_float4(o[0], o[1], o[2], o[3]);
            reinterpret_cast<float4*>(n_out)[2 * n + 1] =
                make_float4(o[4], o[5], o[6], o[7]);
        }
    }
#pragma unroll
    for (int q = 0; q < 8; ++q) {
        const float s = wave_sum(valid ? o[q] : 0.0f);
        if ((t & 63) == 0) npart[t >> 6][q] = s;
    }
    __syncthreads();
    if (t < 8)
        atomicAdd(&n_sum[t], npart[0][t] + npart[1][t] + npart[2][t] + npart[3][t]);
    __threadfence();
    __syncthreads();
    if (t == 0) {
        const int old = atomicAdd(done, 1);
        if (old == (int)gridDim.x - 1) {
            // last block: fused global-MLP update
            __threadfence();
            float gin[17];
#pragma unroll
            for (int k = 0; k < 8; ++k)
                gin[k] = atomicAdd(&n_sum[k], 0.0f) / (float)N;
            float es = 0.0f;
            for (int b = 0; b < 64; ++b) es += ebins[b];
            gin[8] = es * inv_E;
#pragma unroll
            for (int k = 0; k < 8; ++k) gin[9 + k] = gbuf[k];
            float go[8];
#pragma unroll
            for (int q = 0; q < 8; ++q) go[q] = gb2[q];
            for (int j = 0; j < 32; ++j) {
                float hv = gb1[j];
                for (int k = 0; k < 17; ++k) hv = fmaf(gin[k], gW1[k * 32 + j], hv);
                hv = fmaxf(hv, 0.0f);
                for (int q = 0; q < 8; ++q) go[q] = fmaf(hv, gW2[j * 8 + q], go[q]);
            }
#pragma unroll
            for (int q = 0; q < 8; ++q) g_out[q] = go[q];
        }
    }
}

extern "C" void kernel_launch(void* const* d_in, const int* in_sizes, int n_in,
                              void* d_out, int out_size, void* d_ws,
                              size_t ws_size, hipStream_t stream) {
    const float* x = (const float*)d_in[0];
    const int* l_ei = (const int*)d_in[1];
    const int* u_ei = (const int*)d_in[2];
    const float* l_attr = (const float*)d_in[3];
    const float* u_attr = (const float*)d_in[4];
    const float* eW1 = (const float*)d_in[5];
    const float* eb1 = (const float*)d_in[6];
    const float* eW2 = (const float*)d_in[7];
    const float* eb2 = (const float*)d_in[8];
    const float* nW1 = (const float*)d_in[9];
    const float* nb1 = (const float*)d_in[10];
    const float* nW2 = (const float*)d_in[11];
    const float* nb2 = (const float*)d_in[12];
    const float* gW1 = (const float*)d_in[13];
    const float* gb1 = (const float*)d_in[14];
    const float* gW2 = (const float*)d_in[15];
    const float* gb2 = (const float*)d_in[16];

    const int E = in_sizes[3];      // 1,100,000
    const int N = in_sizes[0] / 8;  // 100,000
    const int B = (N + NB_SIZE - 1) >> NB_SHIFT;  // 196 buckets

    // workspace layout (floats)
    float* ws = (float*)d_ws;
    float* l_e = ws;                        // E
    float* u_e = l_e + E;                   // E
    float* l_n = u_e + E;                   // 8N (float4-aligned)
    float* agg = l_n + (size_t)8 * N;       // N
    float* cnt_l = agg + N;                 // N (float counts)
    float* cnt_u = cnt_l + N;               // N
    float* gbuf = cnt_u + N;                // 8
    float* dyn = gbuf + 8;                  // 73: ebins[64] n_sum[8] done[1]
    float* ebins = dyn;
    float* n_sum = dyn + 64;
    int* done = (int*)(dyn + 72);
    u32* hist = (u32*)(dyn + 73);           // 2B
    u32* offs = hist + 2 * B;               // 2(B+1)
    u32* cur = offs + 2 * (B + 1);          // 2B
    u32* list = cur + 2 * B;                // 2E (lower | upper)

    const int* lr = l_ei;
    const int* lc = l_ei + E;
    const int* ur = u_ei;
    const int* uc = u_ei + E;
    const int eg = (E + 255) / 256;
    const int ng = (N + 255) / 256;
    const int sg = (E + SCHUNK - 1) / SCHUNK;
    const float invE = 1.0f / (float)E;
    float* outL = (float*)d_out;
    float* outU = outL + E;
    const u32* offs_l = offs;
    const u32* offs_u = offs + (B + 1);
    const u32* list_l = list;
    const u32* list_u = list + E;

    // ---------------- per-call build of bucketed edge lists ----------------
    hipMemsetAsync(hist, 0, (size_t)(2 * B) * sizeof(u32), stream);
    hipMemsetAsync(gbuf, 0, 8 * sizeof(float), stream);
    hist_kernel<<<dim3(128, 2), 256, 0, stream>>>(lr, ur, hist, E, B);
    scan_kernel<<<1, 64, 0, stream>>>(hist, offs, cur, B);
    scatter_kernel<<<dim3(sg, 2), 256, 0, stream>>>(lr, ur, cur, list, E, B);

    for (int i = 0; i < 3; ++i) {
        const size_t lo = (size_t)i;        // lower-block slice
        const size_t up = (size_t)(3 + i);  // upper-block slice

        // ---------------- lower GraphNet ----------------
        hipMemsetAsync(dyn, 0, 73 * sizeof(float), stream);
        const float* eprev = (i == 0) ? l_attr : l_e;
        if (i == 0)
            edge_kernel<false, true, false, true><<<eg, 256, 0, stream>>>(
                (const float4*)x, lr, lc, eprev, l_attr, eW1 + lo * 832,
                eb1 + lo * 32, eW2 + lo * 32, eb2 + lo, gbuf, l_e, outL, ebins, E);
        else if (i == 1)
            edge_kernel<true, true, false, true><<<eg, 256, 0, stream>>>(
                (const float4*)x, lr, lc, eprev, l_attr, eW1 + lo * 832,
                eb1 + lo * 32, eW2 + lo * 32, eb2 + lo, gbuf, l_e, outL, ebins, E);
        else
            edge_kernel<true, true, true, true><<<eg, 256, 0, stream>>>(
                (const float4*)x, lr, lc, eprev, l_attr, eW1 + lo * 832,
                eb1 + lo * 32, eW2 + lo * 32, eb2 + lo, gbuf, l_e, outL, ebins, E);
        if (i == 0)
            agg_kernel<true><<<B, 1024, 0, stream>>>(list_l, offs_l, lr, l_e,
                                                     agg, cnt_l, N);
        else
            agg_kernel<false><<<B, 1024, 0, stream>>>(list_l, offs_l, lr, l_e,
                                                      agg, cnt_l, N);
        node_kernel<true><<<ng, 256, 0, stream>>>(
            (const float4*)x, agg, cnt_l, gbuf, nW1 + lo * 544, nb1 + lo * 32,
            nW2 + lo * 256, nb2 + lo * 8, l_n, ebins, n_sum, done,
            gW1 + lo * 544, gb1 + lo * 32, gW2 + lo * 256, gb2 + lo * 8, gbuf,
            N, invE);

        // ---------------- upper GraphNet ----------------
        if (i < 2) {
            hipMemsetAsync(dyn, 0, 73 * sizeof(float), stream);
            const float* ueprev = (i == 0) ? u_attr : u_e;
            edge_kernel<false, true, false, true><<<eg, 256, 0, stream>>>(
                (const float4*)l_n, ur, uc, ueprev, nullptr, eW1 + up * 832,
                eb1 + up * 32, eW2 + up * 32, eb2 + up, gbuf, u_e, nullptr,
                ebins, E);
            if (i == 0)
                agg_kernel<true><<<B, 1024, 0, stream>>>(list_u, offs_u, ur,
                                                         u_e, agg, cnt_u, N);
            else
                agg_kernel<false><<<B, 1024, 0, stream>>>(list_u, offs_u, ur,
                                                          u_e, agg, cnt_u, N);
            node_kernel<false><<<ng, 256, 0, stream>>>(
                (const float4*)l_n, agg, cnt_u, gbuf, nW1 + up * 544,
                nb1 + up * 32, nW2 + up * 256, nb2 + up * 8, nullptr, ebins,
                n_sum, done, gW1 + up * 544, gb1 + up * 32, gW2 + up * 256,
                gb2 + up * 8, gbuf, N, invE);
        } else {
            // final upper GraphNet: only edge output needed -> write u_vals
            edge_kernel<false, false, true, false><<<eg, 256, 0, stream>>>(
                (const float4*)l_n, ur, uc, u_e, nullptr, eW1 + up * 832,
                eb1 + up * 32, eW2 + up * 32, eb2 + up, gbuf, nullptr, outU,
                ebins, E);
        }
    }
}

// Round 3
// 677.005 us; speedup vs baseline: 1.2075x; 1.0778x over previous
//
#include <hip/hip_runtime.h>

// NeuralIF GraphNet: 3 layers x (lower GraphNet, upper GraphNet).
// R1: bucketed edge lists + LDS-bin aggregation (no scattered global atomics).
// R2 -> R3: node-mean reduction binned over 64 cache lines (was 391 blocks x 8
// atomics into ONE line -> ~50us serialization); lane-parallel last-block
// global MLP; single upfront memset for all per-GraphNet dynamic regions.

typedef unsigned int u32;

#define NB_SHIFT 9
#define NB_SIZE 512
#define RSTRIDE 1104  // per-GraphNet dyn region: ebins[64] nbins[64*16] done+pad[16]

__device__ __forceinline__ float wave_sum(float v) {
#pragma unroll
    for (int off = 32; off > 0; off >>= 1) v += __shfl_down(v, off, 64);
    return v;
}

// ---------------- bucketed-list build (once per call) ----------------

__global__ __launch_bounds__(256) void hist_kernel(
    const int* __restrict__ lr, const int* __restrict__ ur,
    u32* __restrict__ hist, int E, int B) {
    __shared__ u32 h[256];
    const int t = threadIdx.x;
    if (t < B) h[t] = 0;
    __syncthreads();
    const int s = blockIdx.y;
    const int* rows = s ? ur : lr;
    for (int i = blockIdx.x * 256 + t; i < E; i += gridDim.x * 256)
        atomicAdd(&h[rows[i] >> NB_SHIFT], 1u);
    __syncthreads();
    if (t < B && h[t]) atomicAdd(&hist[s * B + t], h[t]);
}

__global__ void scan_kernel(const u32* __restrict__ hist, u32* __restrict__ offs,
                            u32* __restrict__ cur, int B) {
    if (threadIdx.x == 0) {
        for (int s = 0; s < 2; ++s) {
            u32 acc = 0;
            for (int b = 0; b < B; ++b) {
                offs[s * (B + 1) + b] = acc;
                cur[s * B + b] = acc;
                acc += hist[s * B + b];
            }
            offs[s * (B + 1) + B] = acc;
        }
    }
}

#define SCHUNK 4096
__global__ __launch_bounds__(256) void scatter_kernel(
    const int* __restrict__ lr, const int* __restrict__ ur,
    u32* __restrict__ cur, u32* __restrict__ list, int E, int B) {
    __shared__ u32 lcnt[256], lbase[256];
    const int t = threadIdx.x;
    const int s = blockIdx.y;
    const int* rows = s ? ur : lr;
    u32* mylist = list + (size_t)s * E;
    if (t < B) lcnt[t] = 0;
    __syncthreads();
    const int base_e = blockIdx.x * SCHUNK;
#pragma unroll
    for (int k = 0; k < SCHUNK / 256; ++k) {
        const int e = base_e + k * 256 + t;
        if (e < E) atomicAdd(&lcnt[rows[e] >> NB_SHIFT], 1u);
    }
    __syncthreads();
    if (t < B) {
        const u32 c = lcnt[t];
        lbase[t] = c ? atomicAdd(&cur[s * B + t], c) : 0u;
        lcnt[t] = 0;
    }
    __syncthreads();
#pragma unroll
    for (int k = 0; k < SCHUNK / 256; ++k) {
        const int e = base_e + k * 256 + t;
        if (e < E) {
            const int b = rows[e] >> NB_SHIFT;
            const u32 pos = lbase[b] + atomicAdd(&lcnt[b], 1u);
            mylist[pos] = (u32)e;
        }
    }
}

// ---------------- aggregation: one block owns one bucket ----------------

template <bool COUNT>
__global__ __launch_bounds__(1024) void agg_kernel(
    const u32* __restrict__ list, const u32* __restrict__ offs,
    const int* __restrict__ rows, const float* __restrict__ e_emb,
    float* __restrict__ agg, float* __restrict__ cntf, int N) {
    __shared__ float sbin[NB_SIZE];
    __shared__ float cbin[NB_SIZE];
    const int t = threadIdx.x;
    const int b = blockIdx.x;
    if (t < NB_SIZE) {
        sbin[t] = 0.0f;
        if constexpr (COUNT) cbin[t] = 0.0f;
    }
    __syncthreads();
    const u32 beg = offs[b], end = offs[b + 1];
    for (u32 i = beg + t; i < end; i += 1024) {
        const u32 eid = list[i];
        const float v = e_emb[eid];
        const int r = rows[eid];
        atomicAdd(&sbin[r & (NB_SIZE - 1)], v);
        if constexpr (COUNT) atomicAdd(&cbin[r & (NB_SIZE - 1)], 1.0f);
    }
    __syncthreads();
    const int n0 = b << NB_SHIFT;
    if (t < NB_SIZE && n0 + t < N) {
        agg[n0 + t] = sbin[t];
        if constexpr (COUNT) cntf[n0 + t] = cbin[t];
    }
}

// ---------------- edge MLP ----------------

template <bool SKIP, bool GAGG, bool VALS, bool STORE>
__global__ __launch_bounds__(256) void edge_kernel(
    const float4* __restrict__ xf,       // node features (N,8) as float4 pairs
    const int* __restrict__ rows, const int* __restrict__ cols,
    const float* __restrict__ eprev,     // previous edge embedding (E)
    const float* __restrict__ skipattr,  // original attr (skip col), if SKIP
    const float* __restrict__ W1,        // 26x32 slice (row-major k,j)
    const float* __restrict__ b1,        // 32
    const float* __restrict__ W2,        // 32
    const float* __restrict__ b2,        // 1
    const float* __restrict__ gbuf,      // 8 (current global)
    float* __restrict__ e_out,           // edge emb store (STORE)
    float* __restrict__ vals_out,        // final output segment (VALS)
    float* __restrict__ ebins,           // 64 partial sums for e-mean (GAGG)
    int E) {
    __shared__ float biasE[32];
    __shared__ float wpart[4];
    const int t = threadIdx.x;
    if (t < 32) {
        // fold uniform global contribution + b1 into per-pass bias (once/block)
        float v = b1[t];
#pragma unroll
        for (int k = 0; k < 8; ++k) v = fmaf(gbuf[k], W1[k * 32 + t], v);
        biasE[t] = v;
    }
    __syncthreads();
    const int e = blockIdx.x * 256 + t;
    const bool valid = e < E;
    const int idx = valid ? e : 0;
    const int r = rows[idx];
    const int c = cols[idx];
    const float4 xr0 = xf[2 * r], xr1 = xf[2 * r + 1];
    const float4 xc0 = xf[2 * c], xc1 = xf[2 * c + 1];
    float in[18] = {xr0.x, xr0.y, xr0.z, xr0.w, xr1.x, xr1.y, xr1.z, xr1.w,
                    xc0.x, xc0.y, xc0.z, xc0.w, xc1.x, xc1.y, xc1.z, xc1.w,
                    eprev[idx], 0.0f};
    if constexpr (SKIP) in[17] = skipattr[idx];
    float h[32];
#pragma unroll
    for (int j = 0; j < 8; ++j) {
        const float4 b = reinterpret_cast<const float4*>(biasE)[j];
        h[4 * j + 0] = b.x; h[4 * j + 1] = b.y;
        h[4 * j + 2] = b.z; h[4 * j + 3] = b.w;
    }
    const float* __restrict__ Wk = W1 + 8 * 32;  // rows 8..25 (x[row],x[col],attr)
#pragma unroll
    for (int k = 0; k < 18; ++k) {
        const float v = in[k];
#pragma unroll
        for (int j = 0; j < 32; ++j) h[j] = fmaf(v, Wk[k * 32 + j], h[j]);
    }
    float out = b2[0];
#pragma unroll
    for (int j = 0; j < 32; ++j) out = fmaf(fmaxf(h[j], 0.0f), W2[j], out);

    if (valid) {
        if constexpr (STORE) e_out[e] = out;
        if constexpr (VALS) vals_out[e] = (r == c) ? expf(out) : out;
    }
    if constexpr (GAGG) {
        const float s = wave_sum(valid ? out : 0.0f);
        if ((t & 63) == 0) wpart[t >> 6] = s;
        __syncthreads();
        if (t == 0)
            atomicAdd(&ebins[blockIdx.x & 63],
                      wpart[0] + wpart[1] + wpart[2] + wpart[3]);
    }
}

// ---------------- node MLP (+ fused global MLP in last block) ----------------

template <bool STORE_N>
__global__ __launch_bounds__(256) void node_kernel(
    const float4* __restrict__ xf,  // node features (N,8): x or l_n
    const float* __restrict__ agg_sum, const float* __restrict__ cntf,
    const float* __restrict__ gbuf,
    const float* __restrict__ nW1, const float* __restrict__ nb1,
    const float* __restrict__ nW2, const float* __restrict__ nb2,
    float* __restrict__ n_out,  // l_n (8N) if STORE_N
    float* __restrict__ ebins,  // 64
    float* __restrict__ nbins,  // 64 x 16 (one cache line per bin)
    int* __restrict__ done,
    const float* __restrict__ gW1, const float* __restrict__ gb1,
    const float* __restrict__ gW2, const float* __restrict__ gb2,
    float* __restrict__ g_out,  // 8 (same buffer as gbuf)
    int N, float inv_E) {
    __shared__ float biasN[32];
    __shared__ float npart[4][8];
    const int t = threadIdx.x;
    if (t < 32) {
        float v = nb1[t];
#pragma unroll
        for (int k = 0; k < 8; ++k) v = fmaf(gbuf[k], nW1[k * 32 + t], v);
        biasN[t] = v;
    }
    __syncthreads();
    const int n = blockIdx.x * 256 + t;
    const bool valid = n < N;
    const int idx = valid ? n : 0;
    const float4 x0 = xf[2 * idx], x1 = xf[2 * idx + 1];
    const float agg = agg_sum[idx] / fmaxf(cntf[idx], 1.0f);
    float in[9] = {x0.x, x0.y, x0.z, x0.w, x1.x, x1.y, x1.z, x1.w, agg};
    float h[32];
#pragma unroll
    for (int j = 0; j < 8; ++j) {
        const float4 b = reinterpret_cast<const float4*>(biasN)[j];
        h[4 * j + 0] = b.x; h[4 * j + 1] = b.y;
        h[4 * j + 2] = b.z; h[4 * j + 3] = b.w;
    }
    const float* __restrict__ Wk = nW1 + 8 * 32;
#pragma unroll
    for (int k = 0; k < 9; ++k) {
        const float v = in[k];
#pragma unroll
        for (int j = 0; j < 32; ++j) h[j] = fmaf(v, Wk[k * 32 + j], h[j]);
    }
    float o[8];
#pragma unroll
    for (int q = 0; q < 8; ++q) o[q] = nb2[q];
#pragma unroll
    for (int j = 0; j < 32; ++j) {
        const float hv = fmaxf(h[j], 0.0f);
#pragma unroll
        for (int q = 0; q < 8; ++q) o[q] = fmaf(hv, nW2[j * 8 + q], o[q]);
    }
    if constexpr (STORE_N) {
        if (valid) {
            reinterpret_cast<float4*>(n_out)[2 * n] =
                make_float4(o[0], o[1], o[2], o[3]);
            reinterpret_cast<float4*>(n_out)[2 * n + 1] =
                make_float4(o[4], o[5], o[6], o[7]);
        }
    }
#pragma unroll
    for (int q = 0; q < 8; ++q) {
        const float s = wave_sum(valid ? o[q] : 0.0f);
        if ((t & 63) == 0) npart[t >> 6][q] = s;
    }
    __syncthreads();
    if (t < 8)
        atomicAdd(&nbins[(blockIdx.x & 63) * 16 + t],
                  npart[0][t] + npart[1][t] + npart[2][t] + npart[3][t]);
    __threadfence();
    __syncthreads();
    if (t < 64) {
        int old = 0;
        if (t == 0) old = atomicAdd(done, 1);
        old = __shfl(old, 0, 64);
        if (old == (int)gridDim.x - 1) {
            // last block: fused global-MLP update, lane-parallel
            __threadfence();
            float nb[8];
#pragma unroll
            for (int q = 0; q < 8; ++q)
                nb[q] = atomicAdd(&nbins[t * 16 + q], 0.0f);  // atomic read
            const float eb = atomicAdd(&ebins[t], 0.0f);
            const float es = wave_sum(eb);
            float gin[17];
#pragma unroll
            for (int q = 0; q < 8; ++q) {
                const float s = wave_sum(nb[q]);
                gin[q] = __shfl(s, 0, 64) / (float)N;
            }
            gin[8] = __shfl(es, 0, 64) * inv_E;
#pragma unroll
            for (int k = 0; k < 8; ++k) gin[9 + k] = gbuf[k];
            float hv = 0.0f;
            if (t < 32) {
                hv = gb1[t];
#pragma unroll
                for (int k = 0; k < 17; ++k)
                    hv = fmaf(gin[k], gW1[k * 32 + t], hv);
                hv = fmaxf(hv, 0.0f);
            }
#pragma unroll
            for (int q = 0; q < 8; ++q) {
                const float c = (t < 32) ? hv * gW2[t * 8 + q] : 0.0f;
                const float s = wave_sum(c);
                if (t == 0) g_out[q] = gb2[q] + s;
            }
        }
    }
}

extern "C" void kernel_launch(void* const* d_in, const int* in_sizes, int n_in,
                              void* d_out, int out_size, void* d_ws,
                              size_t ws_size, hipStream_t stream) {
    const float* x = (const float*)d_in[0];
    const int* l_ei = (const int*)d_in[1];
    const int* u_ei = (const int*)d_in[2];
    const float* l_attr = (const float*)d_in[3];
    const float* u_attr = (const float*)d_in[4];
    const float* eW1 = (const float*)d_in[5];
    const float* eb1 = (const float*)d_in[6];
    const float* eW2 = (const float*)d_in[7];
    const float* eb2 = (const float*)d_in[8];
    const float* nW1 = (const float*)d_in[9];
    const float* nb1 = (const float*)d_in[10];
    const float* nW2 = (const float*)d_in[11];
    const float* nb2 = (const float*)d_in[12];
    const float* gW1 = (const float*)d_in[13];
    const float* gb1 = (const float*)d_in[14];
    const float* gW2 = (const float*)d_in[15];
    const float* gb2 = (const float*)d_in[16];

    const int E = in_sizes[3];      // 1,100,000
    const int N = in_sizes[0] / 8;  // 100,000
    const int B = (N + NB_SIZE - 1) >> NB_SHIFT;  // 196 buckets

    // workspace layout (floats)
    float* ws = (float*)d_ws;
    float* l_e = ws;                      // E
    float* u_e = l_e + E;                 // E
    float* l_n = u_e + E;                 // 8N (float4-aligned)
    float* agg = l_n + (size_t)8 * N;     // N
    float* cnt_l = agg + N;               // N (float counts)
    float* cnt_u = cnt_l + N;             // N
    float* gbuf = cnt_u + N;              // 8   -- zeroed region starts here
    u32* hist = (u32*)(gbuf + 8);         // 2B
    float* dyn_all = (float*)(hist + 2 * B);  // 5 * RSTRIDE
    u32* offs = (u32*)(dyn_all + 5 * RSTRIDE);  // 2(B+1)
    u32* cur = offs + 2 * (B + 1);        // 2B
    u32* list = cur + 2 * B;              // 2E (lower | upper)

    const int* lr = l_ei;
    const int* lc = l_ei + E;
    const int* ur = u_ei;
    const int* uc = u_ei + E;
    const int eg = (E + 255) / 256;
    const int ng = (N + 255) / 256;
    const int sg = (E + SCHUNK - 1) / SCHUNK;
    const float invE = 1.0f / (float)E;
    float* outL = (float*)d_out;
    float* outU = outL + E;
    const u32* offs_l = offs;
    const u32* offs_u = offs + (B + 1);
    const u32* list_l = list;
    const u32* list_u = list + E;

    // one memset: gbuf + hist + all 5 dyn regions
    hipMemsetAsync(gbuf, 0, (size_t)(8 + 2 * B + 5 * RSTRIDE) * sizeof(float),
                   stream);
    hist_kernel<<<dim3(128, 2), 256, 0, stream>>>(lr, ur, hist, E, B);
    scan_kernel<<<1, 64, 0, stream>>>(hist, offs, cur, B);
    scatter_kernel<<<dim3(sg, 2), 256, 0, stream>>>(lr, ur, cur, list, E, B);

    int reg = 0;  // dyn region index (one per full GraphNet)
    for (int i = 0; i < 3; ++i) {
        const size_t lo = (size_t)i;        // lower-block slice
        const size_t up = (size_t)(3 + i);  // upper-block slice

        // ---------------- lower GraphNet ----------------
        float* ebins = dyn_all + (size_t)reg * RSTRIDE;
        float* nbins = ebins + 64;
        int* done = (int*)(nbins + 1024);
        ++reg;
        const float* eprev = (i == 0) ? l_attr : l_e;
        if (i == 0)
            edge_kernel<false, true, false, true><<<eg, 256, 0, stream>>>(
                (const float4*)x, lr, lc, eprev, l_attr, eW1 + lo * 832,
                eb1 + lo * 32, eW2 + lo * 32, eb2 + lo, gbuf, l_e, outL, ebins, E);
        else if (i == 1)
            edge_kernel<true, true, false, true><<<eg, 256, 0, stream>>>(
                (const float4*)x, lr, lc, eprev, l_attr, eW1 + lo * 832,
                eb1 + lo * 32, eW2 + lo * 32, eb2 + lo, gbuf, l_e, outL, ebins, E);
        else
            edge_kernel<true, true, true, true><<<eg, 256, 0, stream>>>(
                (const float4*)x, lr, lc, eprev, l_attr, eW1 + lo * 832,
                eb1 + lo * 32, eW2 + lo * 32, eb2 + lo, gbuf, l_e, outL, ebins, E);
        if (i == 0)
            agg_kernel<true><<<B, 1024, 0, stream>>>(list_l, offs_l, lr, l_e,
                                                     agg, cnt_l, N);
        else
            agg_kernel<false><<<B, 1024, 0, stream>>>(list_l, offs_l, lr, l_e,
                                                      agg, cnt_l, N);
        node_kernel<true><<<ng, 256, 0, stream>>>(
            (const float4*)x, agg, cnt_l, gbuf, nW1 + lo * 544, nb1 + lo * 32,
            nW2 + lo * 256, nb2 + lo * 8, l_n, ebins, nbins, done,
            gW1 + lo * 544, gb1 + lo * 32, gW2 + lo * 256, gb2 + lo * 8, gbuf,
            N, invE);

        // ---------------- upper GraphNet ----------------
        if (i < 2) {
            float* ebins2 = dyn_all + (size_t)reg * RSTRIDE;
            float* nbins2 = ebins2 + 64;
            int* done2 = (int*)(nbins2 + 1024);
            ++reg;
            const float* ueprev = (i == 0) ? u_attr : u_e;
            edge_kernel<false, true, false, true><<<eg, 256, 0, stream>>>(
                (const float4*)l_n, ur, uc, ueprev, nullptr, eW1 + up * 832,
                eb1 + up * 32, eW2 + up * 32, eb2 + up, gbuf, u_e, nullptr,
                ebins2, E);
            if (i == 0)
                agg_kernel<true><<<B, 1024, 0, stream>>>(list_u, offs_u, ur,
                                                         u_e, agg, cnt_u, N);
            else
                agg_kernel<false><<<B, 1024, 0, stream>>>(list_u, offs_u, ur,
                                                          u_e, agg, cnt_u, N);
            node_kernel<false><<<ng, 256, 0, stream>>>(
                (const float4*)l_n, agg, cnt_u, gbuf, nW1 + up * 544,
                nb1 + up * 32, nW2 + up * 256, nb2 + up * 8, nullptr, ebins2,
                nbins2, done2, gW1 + up * 544, gb1 + up * 32, gW2 + up * 256,
                gb2 + up * 8, gbuf, N, invE);
        } else {
            // final upper GraphNet: only edge output needed -> write u_vals
            edge_kernel<false, false, true, false><<<eg, 256, 0, stream>>>(
                (const float4*)l_n, ur, uc, u_e, nullptr, eW1 + up * 832,
                eb1 + up * 32, eW2 + up * 32, eb2 + up, gbuf, nullptr, outU,
                ebins, E);
        }
    }
}

// Round 4
// 570.000 us; speedup vs baseline: 1.4342x; 1.1877x over previous
//
#include <hip/hip_runtime.h>

// NeuralIF GraphNet: 3 layers x (lower GraphNet, upper GraphNet).
// R1: bucketed edge lists + LDS-bin aggregation (no scattered global atomics).
// R3: binned node-mean partials.
// R4: removed done-counter + __threadfence + fused last-block global MLP from
// node_kernel (391 agent-scope fences were ~90% of its 75us). Global MLP is
// now a separate 1-block kernel; kernel boundary provides visibility.

typedef unsigned int u32;

#define NB_SHIFT 9
#define NB_SIZE 512
#define RSTRIDE 1104  // per-GraphNet dyn region: ebins[64] nbins[64*16] pad

__device__ __forceinline__ float wave_sum(float v) {
#pragma unroll
    for (int off = 32; off > 0; off >>= 1) v += __shfl_down(v, off, 64);
    return v;
}

// ---------------- bucketed-list build (once per call) ----------------

__global__ __launch_bounds__(256) void hist_kernel(
    const int* __restrict__ lr, const int* __restrict__ ur,
    u32* __restrict__ hist, int E, int B) {
    __shared__ u32 h[256];
    const int t = threadIdx.x;
    if (t < B) h[t] = 0;
    __syncthreads();
    const int s = blockIdx.y;
    const int* rows = s ? ur : lr;
    for (int i = blockIdx.x * 256 + t; i < E; i += gridDim.x * 256)
        atomicAdd(&h[rows[i] >> NB_SHIFT], 1u);
    __syncthreads();
    if (t < B && h[t]) atomicAdd(&hist[s * B + t], h[t]);
}

__global__ void scan_kernel(const u32* __restrict__ hist, u32* __restrict__ offs,
                            u32* __restrict__ cur, int B) {
    if (threadIdx.x == 0) {
        for (int s = 0; s < 2; ++s) {
            u32 acc = 0;
            for (int b = 0; b < B; ++b) {
                offs[s * (B + 1) + b] = acc;
                cur[s * B + b] = acc;
                acc += hist[s * B + b];
            }
            offs[s * (B + 1) + B] = acc;
        }
    }
}

#define SCHUNK 4096
__global__ __launch_bounds__(256) void scatter_kernel(
    const int* __restrict__ lr, const int* __restrict__ ur,
    u32* __restrict__ cur, u32* __restrict__ list, int E, int B) {
    __shared__ u32 lcnt[256], lbase[256];
    const int t = threadIdx.x;
    const int s = blockIdx.y;
    const int* rows = s ? ur : lr;
    u32* mylist = list + (size_t)s * E;
    if (t < B) lcnt[t] = 0;
    __syncthreads();
    const int base_e = blockIdx.x * SCHUNK;
#pragma unroll
    for (int k = 0; k < SCHUNK / 256; ++k) {
        const int e = base_e + k * 256 + t;
        if (e < E) atomicAdd(&lcnt[rows[e] >> NB_SHIFT], 1u);
    }
    __syncthreads();
    if (t < B) {
        const u32 c = lcnt[t];
        lbase[t] = c ? atomicAdd(&cur[s * B + t], c) : 0u;
        lcnt[t] = 0;
    }
    __syncthreads();
#pragma unroll
    for (int k = 0; k < SCHUNK / 256; ++k) {
        const int e = base_e + k * 256 + t;
        if (e < E) {
            const int b = rows[e] >> NB_SHIFT;
            const u32 pos = lbase[b] + atomicAdd(&lcnt[b], 1u);
            mylist[pos] = (u32)e;
        }
    }
}

// ---------------- aggregation: one block owns one bucket ----------------

template <bool COUNT>
__global__ __launch_bounds__(1024) void agg_kernel(
    const u32* __restrict__ list, const u32* __restrict__ offs,
    const int* __restrict__ rows, const float* __restrict__ e_emb,
    float* __restrict__ agg, float* __restrict__ cntf, int N) {
    __shared__ float sbin[NB_SIZE];
    __shared__ float cbin[NB_SIZE];
    const int t = threadIdx.x;
    const int b = blockIdx.x;
    if (t < NB_SIZE) {
        sbin[t] = 0.0f;
        if constexpr (COUNT) cbin[t] = 0.0f;
    }
    __syncthreads();
    const u32 beg = offs[b], end = offs[b + 1];
    for (u32 i = beg + t; i < end; i += 1024) {
        const u32 eid = list[i];
        const float v = e_emb[eid];
        const int r = rows[eid];
        atomicAdd(&sbin[r & (NB_SIZE - 1)], v);
        if constexpr (COUNT) atomicAdd(&cbin[r & (NB_SIZE - 1)], 1.0f);
    }
    __syncthreads();
    const int n0 = b << NB_SHIFT;
    if (t < NB_SIZE && n0 + t < N) {
        agg[n0 + t] = sbin[t];
        if constexpr (COUNT) cntf[n0 + t] = cbin[t];
    }
}

// ---------------- edge MLP ----------------

template <bool SKIP, bool GAGG, bool VALS, bool STORE>
__global__ __launch_bounds__(256) void edge_kernel(
    const float4* __restrict__ xf,       // node features (N,8) as float4 pairs
    const int* __restrict__ rows, const int* __restrict__ cols,
    const float* __restrict__ eprev,     // previous edge embedding (E)
    const float* __restrict__ skipattr,  // original attr (skip col), if SKIP
    const float* __restrict__ W1,        // 26x32 slice (row-major k,j)
    const float* __restrict__ b1,        // 32
    const float* __restrict__ W2,        // 32
    const float* __restrict__ b2,        // 1
    const float* __restrict__ gbuf,      // 8 (current global)
    float* __restrict__ e_out,           // edge emb store (STORE)
    float* __restrict__ vals_out,        // final output segment (VALS)
    float* __restrict__ ebins,           // 64 partial sums for e-mean (GAGG)
    int E) {
    __shared__ float biasE[32];
    __shared__ float wpart[4];
    const int t = threadIdx.x;
    if (t < 32) {
        // fold uniform global contribution + b1 into per-pass bias (once/block)
        float v = b1[t];
#pragma unroll
        for (int k = 0; k < 8; ++k) v = fmaf(gbuf[k], W1[k * 32 + t], v);
        biasE[t] = v;
    }
    __syncthreads();
    const int e = blockIdx.x * 256 + t;
    const bool valid = e < E;
    const int idx = valid ? e : 0;
    const int r = rows[idx];
    const int c = cols[idx];
    const float4 xr0 = xf[2 * r], xr1 = xf[2 * r + 1];
    const float4 xc0 = xf[2 * c], xc1 = xf[2 * c + 1];
    float in[18] = {xr0.x, xr0.y, xr0.z, xr0.w, xr1.x, xr1.y, xr1.z, xr1.w,
                    xc0.x, xc0.y, xc0.z, xc0.w, xc1.x, xc1.y, xc1.z, xc1.w,
                    eprev[idx], 0.0f};
    if constexpr (SKIP) in[17] = skipattr[idx];
    float h[32];
#pragma unroll
    for (int j = 0; j < 8; ++j) {
        const float4 b = reinterpret_cast<const float4*>(biasE)[j];
        h[4 * j + 0] = b.x; h[4 * j + 1] = b.y;
        h[4 * j + 2] = b.z; h[4 * j + 3] = b.w;
    }
    const float* __restrict__ Wk = W1 + 8 * 32;  // rows 8..25 (x[row],x[col],attr)
#pragma unroll
    for (int k = 0; k < 18; ++k) {
        const float v = in[k];
#pragma unroll
        for (int j = 0; j < 32; ++j) h[j] = fmaf(v, Wk[k * 32 + j], h[j]);
    }
    float out = b2[0];
#pragma unroll
    for (int j = 0; j < 32; ++j) out = fmaf(fmaxf(h[j], 0.0f), W2[j], out);

    if (valid) {
        if constexpr (STORE) e_out[e] = out;
        if constexpr (VALS) vals_out[e] = (r == c) ? expf(out) : out;
    }
    if constexpr (GAGG) {
        const float s = wave_sum(valid ? out : 0.0f);
        if ((t & 63) == 0) wpart[t >> 6] = s;
        __syncthreads();
        if (t == 0)
            atomicAdd(&ebins[blockIdx.x & 63],
                      wpart[0] + wpart[1] + wpart[2] + wpart[3]);
    }
}

// ---------------- node MLP (pure; no fences, no global reduction tail) ------

template <bool STORE_N>
__global__ __launch_bounds__(256) void node_kernel(
    const float4* __restrict__ xf,  // node features (N,8): x or l_n
    const float* __restrict__ agg_sum, const float* __restrict__ cntf,
    const float* __restrict__ gbuf,
    const float* __restrict__ nW1, const float* __restrict__ nb1,
    const float* __restrict__ nW2, const float* __restrict__ nb2,
    float* __restrict__ n_out,  // l_n (8N) if STORE_N
    float* __restrict__ nbins,  // 64 x 16 (one cache line per bin)
    int N) {
    __shared__ float biasN[32];
    __shared__ float npart[4][8];
    const int t = threadIdx.x;
    if (t < 32) {
        float v = nb1[t];
#pragma unroll
        for (int k = 0; k < 8; ++k) v = fmaf(gbuf[k], nW1[k * 32 + t], v);
        biasN[t] = v;
    }
    __syncthreads();
    const int n = blockIdx.x * 256 + t;
    const bool valid = n < N;
    const int idx = valid ? n : 0;
    const float4 x0 = xf[2 * idx], x1 = xf[2 * idx + 1];
    const float agg = agg_sum[idx] / fmaxf(cntf[idx], 1.0f);
    float in[9] = {x0.x, x0.y, x0.z, x0.w, x1.x, x1.y, x1.z, x1.w, agg};
    float h[32];
#pragma unroll
    for (int j = 0; j < 8; ++j) {
        const float4 b = reinterpret_cast<const float4*>(biasN)[j];
        h[4 * j + 0] = b.x; h[4 * j + 1] = b.y;
        h[4 * j + 2] = b.z; h[4 * j + 3] = b.w;
    }
    const float* __restrict__ Wk = nW1 + 8 * 32;
#pragma unroll
    for (int k = 0; k < 9; ++k) {
        const float v = in[k];
#pragma unroll
        for (int j = 0; j < 32; ++j) h[j] = fmaf(v, Wk[k * 32 + j], h[j]);
    }
    float o[8];
#pragma unroll
    for (int q = 0; q < 8; ++q) o[q] = nb2[q];
#pragma unroll
    for (int j = 0; j < 32; ++j) {
        const float hv = fmaxf(h[j], 0.0f);
#pragma unroll
        for (int q = 0; q < 8; ++q) o[q] = fmaf(hv, nW2[j * 8 + q], o[q]);
    }
    if constexpr (STORE_N) {
        if (valid) {
            reinterpret_cast<float4*>(n_out)[2 * n] =
                make_float4(o[0], o[1], o[2], o[3]);
            reinterpret_cast<float4*>(n_out)[2 * n + 1] =
                make_float4(o[4], o[5], o[6], o[7]);
        }
    }
#pragma unroll
    for (int q = 0; q < 8; ++q) {
        const float s = wave_sum(valid ? o[q] : 0.0f);
        if ((t & 63) == 0) npart[t >> 6][q] = s;
    }
    __syncthreads();
    if (t < 8)
        atomicAdd(&nbins[(blockIdx.x & 63) * 16 + t],
                  npart[0][t] + npart[1][t] + npart[2][t] + npart[3][t]);
}

// ---------------- global MLP: 1 block, 64 threads ----------------

__global__ __launch_bounds__(64) void global_kernel(
    const float* __restrict__ ebins,  // 64
    const float* __restrict__ nbins,  // 64 x 16
    const float* __restrict__ gW1, const float* __restrict__ gb1,
    const float* __restrict__ gW2, const float* __restrict__ gb2,
    float* __restrict__ gbuf,  // 8: read old, write new
    int N, float inv_E) {
    const int t = threadIdx.x;
    float nb[8];
#pragma unroll
    for (int q = 0; q < 8; ++q) nb[q] = nbins[t * 16 + q];
    const float eb = ebins[t];
    float gin[17];
#pragma unroll
    for (int q = 0; q < 8; ++q) {
        const float s = wave_sum(nb[q]);
        gin[q] = __shfl(s, 0, 64) / (float)N;
    }
    const float es = wave_sum(eb);
    gin[8] = __shfl(es, 0, 64) * inv_E;
#pragma unroll
    for (int k = 0; k < 8; ++k) gin[9 + k] = gbuf[k];
    float hv = 0.0f;
    if (t < 32) {
        hv = gb1[t];
#pragma unroll
        for (int k = 0; k < 17; ++k) hv = fmaf(gin[k], gW1[k * 32 + t], hv);
        hv = fmaxf(hv, 0.0f);
    }
#pragma unroll
    for (int q = 0; q < 8; ++q) {
        const float c = (t < 32) ? hv * gW2[t * 8 + q] : 0.0f;
        const float s = wave_sum(c);
        if (t == 0) gbuf[q] = gb2[q] + s;
    }
}

extern "C" void kernel_launch(void* const* d_in, const int* in_sizes, int n_in,
                              void* d_out, int out_size, void* d_ws,
                              size_t ws_size, hipStream_t stream) {
    const float* x = (const float*)d_in[0];
    const int* l_ei = (const int*)d_in[1];
    const int* u_ei = (const int*)d_in[2];
    const float* l_attr = (const float*)d_in[3];
    const float* u_attr = (const float*)d_in[4];
    const float* eW1 = (const float*)d_in[5];
    const float* eb1 = (const float*)d_in[6];
    const float* eW2 = (const float*)d_in[7];
    const float* eb2 = (const float*)d_in[8];
    const float* nW1 = (const float*)d_in[9];
    const float* nb1 = (const float*)d_in[10];
    const float* nW2 = (const float*)d_in[11];
    const float* nb2 = (const float*)d_in[12];
    const float* gW1 = (const float*)d_in[13];
    const float* gb1 = (const float*)d_in[14];
    const float* gW2 = (const float*)d_in[15];
    const float* gb2 = (const float*)d_in[16];

    const int E = in_sizes[3];      // 1,100,000
    const int N = in_sizes[0] / 8;  // 100,000
    const int B = (N + NB_SIZE - 1) >> NB_SHIFT;  // 196 buckets

    // workspace layout (floats)
    float* ws = (float*)d_ws;
    float* l_e = ws;                      // E
    float* u_e = l_e + E;                 // E
    float* l_n = u_e + E;                 // 8N (float4-aligned)
    float* agg = l_n + (size_t)8 * N;     // N
    float* cnt_l = agg + N;               // N (float counts)
    float* cnt_u = cnt_l + N;             // N
    float* gbuf = cnt_u + N;              // 8   -- zeroed region starts here
    u32* hist = (u32*)(gbuf + 8);         // 2B
    float* dyn_all = (float*)(hist + 2 * B);    // 5 * RSTRIDE
    u32* offs = (u32*)(dyn_all + 5 * RSTRIDE);  // 2(B+1)
    u32* cur = offs + 2 * (B + 1);        // 2B
    u32* list = cur + 2 * B;              // 2E (lower | upper)

    const int* lr = l_ei;
    const int* lc = l_ei + E;
    const int* ur = u_ei;
    const int* uc = u_ei + E;
    const int eg = (E + 255) / 256;
    const int ng = (N + 255) / 256;
    const int sg = (E + SCHUNK - 1) / SCHUNK;
    const float invE = 1.0f / (float)E;
    float* outL = (float*)d_out;
    float* outU = outL + E;
    const u32* offs_l = offs;
    const u32* offs_u = offs + (B + 1);
    const u32* list_l = list;
    const u32* list_u = list + E;

    // one memset: gbuf + hist + all 5 dyn regions
    hipMemsetAsync(gbuf, 0, (size_t)(8 + 2 * B + 5 * RSTRIDE) * sizeof(float),
                   stream);
    hist_kernel<<<dim3(128, 2), 256, 0, stream>>>(lr, ur, hist, E, B);
    scan_kernel<<<1, 64, 0, stream>>>(hist, offs, cur, B);
    scatter_kernel<<<dim3(sg, 2), 256, 0, stream>>>(lr, ur, cur, list, E, B);

    int reg = 0;  // dyn region index (one per full GraphNet)
    for (int i = 0; i < 3; ++i) {
        const size_t lo = (size_t)i;        // lower-block slice
        const size_t up = (size_t)(3 + i);  // upper-block slice

        // ---------------- lower GraphNet ----------------
        float* ebins = dyn_all + (size_t)reg * RSTRIDE;
        float* nbins = ebins + 64;
        ++reg;
        const float* eprev = (i == 0) ? l_attr : l_e;
        if (i == 0)
            edge_kernel<false, true, false, true><<<eg, 256, 0, stream>>>(
                (const float4*)x, lr, lc, eprev, l_attr, eW1 + lo * 832,
                eb1 + lo * 32, eW2 + lo * 32, eb2 + lo, gbuf, l_e, outL, ebins, E);
        else if (i == 1)
            edge_kernel<true, true, false, true><<<eg, 256, 0, stream>>>(
                (const float4*)x, lr, lc, eprev, l_attr, eW1 + lo * 832,
                eb1 + lo * 32, eW2 + lo * 32, eb2 + lo, gbuf, l_e, outL, ebins, E);
        else
            edge_kernel<true, true, true, true><<<eg, 256, 0, stream>>>(
                (const float4*)x, lr, lc, eprev, l_attr, eW1 + lo * 832,
                eb1 + lo * 32, eW2 + lo * 32, eb2 + lo, gbuf, l_e, outL, ebins, E);
        if (i == 0)
            agg_kernel<true><<<B, 1024, 0, stream>>>(list_l, offs_l, lr, l_e,
                                                     agg, cnt_l, N);
        else
            agg_kernel<false><<<B, 1024, 0, stream>>>(list_l, offs_l, lr, l_e,
                                                      agg, cnt_l, N);
        node_kernel<true><<<ng, 256, 0, stream>>>(
            (const float4*)x, agg, cnt_l, gbuf, nW1 + lo * 544, nb1 + lo * 32,
            nW2 + lo * 256, nb2 + lo * 8, l_n, nbins, N);
        global_kernel<<<1, 64, 0, stream>>>(ebins, nbins, gW1 + lo * 544,
                                            gb1 + lo * 32, gW2 + lo * 256,
                                            gb2 + lo * 8, gbuf, N, invE);

        // ---------------- upper GraphNet ----------------
        if (i < 2) {
            float* ebins2 = dyn_all + (size_t)reg * RSTRIDE;
            float* nbins2 = ebins2 + 64;
            ++reg;
            const float* ueprev = (i == 0) ? u_attr : u_e;
            edge_kernel<false, true, false, true><<<eg, 256, 0, stream>>>(
                (const float4*)l_n, ur, uc, ueprev, nullptr, eW1 + up * 832,
                eb1 + up * 32, eW2 + up * 32, eb2 + up, gbuf, u_e, nullptr,
                ebins2, E);
            if (i == 0)
                agg_kernel<true><<<B, 1024, 0, stream>>>(list_u, offs_u, ur,
                                                         u_e, agg, cnt_u, N);
            else
                agg_kernel<false><<<B, 1024, 0, stream>>>(list_u, offs_u, ur,
                                                          u_e, agg, cnt_u, N);
            node_kernel<false><<<ng, 256, 0, stream>>>(
                (const float4*)l_n, agg, cnt_u, gbuf, nW1 + up * 544,
                nb1 + up * 32, nW2 + up * 256, nb2 + up * 8, nullptr, nbins2,
                N);
            global_kernel<<<1, 64, 0, stream>>>(ebins2, nbins2, gW1 + up * 544,
                                                gb1 + up * 32, gW2 + up * 256,
                                                gb2 + up * 8, gbuf, N, invE);
        } else {
            // final upper GraphNet: only edge output needed -> write u_vals
            edge_kernel<false, false, true, false><<<eg, 256, 0, stream>>>(
                (const float4*)l_n, ur, uc, u_e, nullptr, eW1 + up * 832,
                eb1 + up * 32, eW2 + up * 32, eb2 + up, gbuf, nullptr, outU,
                ebins, E);
        }
    }
}